// Round 20
// baseline (107.687 us; speedup 1.0000x reference)
//
#include <hip/hip_runtime.h>

#define NB 16
#define NH 256
#define NL 4096
#define NN 32

typedef short s8v __attribute__((ext_vector_type(8)));
typedef float f4v __attribute__((ext_vector_type(4)));
typedef unsigned short u8h __attribute__((ext_vector_type(8)));

__device__ __forceinline__ unsigned short f2bf(float x) {
    unsigned int u = __float_as_uint(x);
    unsigned int r = u + 0x7FFFu + ((u >> 16) & 1u);
    return (unsigned short)(r >> 16);
}
__device__ __forceinline__ float bf2f(unsigned short b) {
    return __uint_as_float(((unsigned int)b) << 16);
}
// HW pack: two f32 -> one u32 holding (lo=src0, hi=src1) as bf16 (RNE).
__device__ __forceinline__ unsigned int cvt_pk_bf16(float lo, float hi) {
    unsigned int r;
    asm("v_cvt_pk_bf16_f32 %0, %1, %2" : "=v"(r) : "v"(lo), "v"(hi));
    return r;
}

// ---------- merged precompute (unchanged) ----------
__global__ __launch_bounds__(64) void precompute_kernel(
        const float* __restrict__ log_dt,
        const float* __restrict__ Cr,
        const float* __restrict__ Ci,
        const float* __restrict__ lar,
        const float* __restrict__ aim,
        const float* __restrict__ Dvec,
        float* __restrict__ w32c,
        unsigned short* __restrict__ Mp,
        unsigned short* __restrict__ Em,
        unsigned short* __restrict__ Tm,
        const float* __restrict__ W,
        unsigned short* __restrict__ Wbf) {
    const int h = blockIdx.x;
    const int tid = threadIdx.x;
    __shared__ float sRe[32][33];
    __shared__ float sTd[32];
    __shared__ unsigned short sMp[64 * 32];
    __shared__ unsigned short sEm[32 * 64];

    if (tid < 32) {
        const int n = tid;
        const int idx = h * 32 + n;
        float dt = expf(log_dt[h]);
        float ar = -expf(lar[idx]);
        float ai = aim[idx];
        float dar = ar * dt, dai = ai * dt;
        float er = expf(dar);
        float wr = er * cosf(dai), wi = er * sinf(dai);
        float Er = wr - 1.0f, Ei = wi;
        float den = ar * ar + ai * ai;
        float fr = (Er * ar + Ei * ai) / den;
        float fi = (Ei * ar - Er * ai) / den;
        float cr = Cr[idx], ci = Ci[idx];
        float c2r = 2.0f * (cr * fr - ci * fi);
        float c2i = 2.0f * (cr * fi + ci * fr);
        float e32 = expf(32.0f * dar);
        w32c[h * 64 + 2 * n]     = e32 * cosf(32.0f * dai);
        w32c[h * 64 + 2 * n + 1] = e32 * sinf(32.0f * dai);
        float pr = 1.0f, pi = 0.0f;
        for (int e = 0; e < 32; ++e) {
            sMp[(2 * n) * 32 + (31 - e)]     = f2bf(pr);
            sMp[(2 * n + 1) * 32 + (31 - e)] = f2bf(pi);
            float npr = pr * wr - pi * wi;
            pi = fmaf(pr, wi, pi * wr);
            pr = npr;
        }
        float gr = c2r, gi = c2i;
        for (int e = 0; e <= 32; ++e) {
            if (e < 32) sRe[e][n] = gr;
            if (e >= 1) {
                sEm[(e - 1) * 64 + 2 * n]     = f2bf(gr);
                sEm[(e - 1) * 64 + 2 * n + 1] = f2bf(-gi);
            }
            float ngr = gr * wr - gi * wi;
            gi = fmaf(gr, wi, gi * wr);
            gr = ngr;
        }
    }
    __syncthreads();
    if (tid < 32) {
        float a = 0.0f;
        #pragma unroll
        for (int n = 0; n < 32; ++n) a += sRe[tid][n];
        sTd[tid] = a;
    }
    __syncthreads();
    const float dh = Dvec[h];
    unsigned short* tmh = Tm + h * 1024;
    for (int i = 0; i < 16; ++i) {
        int idx = tid * 16 + i;
        int j = idx >> 5, tt = idx & 31;
        float v = (j >= tt) ? sTd[j - tt] : 0.0f;
        if (j == tt) v += dh;
        tmh[idx] = f2bf(v);
    }
    uint4* mp4 = (uint4*)(Mp + h * 2048);
    uint4* em4 = (uint4*)(Em + h * 2048);
    const uint4* smp4 = (const uint4*)sMp;
    const uint4* sem4 = (const uint4*)sEm;
    #pragma unroll
    for (int k = 0; k < 4; ++k) {
        mp4[k * 64 + tid] = smp4[k * 64 + tid];
        em4[k * 64 + tid] = sem4[k * 64 + tid];
    }
    const int gidx = h * 64 + tid;
    #pragma unroll
    for (int k = 0; k < 2; ++k) {
        int i = gidx + k * (NH * 64);
        float4 v = ((const float4*)W)[i];
        ushort4 o;
        o.x = f2bf(v.x); o.y = f2bf(v.y); o.z = f2bf(v.z); o.w = f2bf(v.w);
        ((ushort4*)Wbf)[i] = o;
    }
}

// ---------- MFMA chunked scan: 8-segment phase B on all 4 waves (unchanged) ----------
__global__ __launch_bounds__(256) void scan_mfma_kernel(
        const float* __restrict__ u,
        const float* __restrict__ w32c,
        const unsigned short* __restrict__ Mp,
        const unsigned short* __restrict__ Tm,
        const unsigned short* __restrict__ Em,
        unsigned short* __restrict__ ybf) {
    const int bh = blockIdx.x;
    const int h = bh & (NH - 1);
    const int tid = threadIdx.x;
    const int lane = tid & 63;
    const int wv = tid >> 6;
    const int g = lane >> 4, c = lane & 15;

    __shared__ float ldsT[512];
    __shared__ __align__(16) unsigned int ldsP[128 * 36];

    s8v bu[2];
    #pragma unroll
    for (int ntl = 0; ntl < 2; ++ntl) {
        const float* usrc = u + (size_t)bh * NL + (((2 * wv + ntl) * 16 + c) << 5) + g * 8;
        float4 x0 = *(const float4*)usrc;
        float4 x1 = *(const float4*)(usrc + 4);
        union { unsigned int w[4]; s8v v; } cv;
        cv.w[0] = cvt_pk_bf16(x0.x, x0.y);
        cv.w[1] = cvt_pk_bf16(x0.z, x0.w);
        cv.w[2] = cvt_pk_bf16(x1.x, x1.y);
        cv.w[3] = cvt_pk_bf16(x1.z, x1.w);
        bu[ntl] = cv.v;
    }

    const unsigned short* mph = Mp + h * 2048;
    f4v p1[4][2];
    #pragma unroll
    for (int mt = 0; mt < 4; ++mt) {
        s8v am = *(const s8v*)(mph + (mt * 16 + c) * 32 + g * 8);
        p1[mt][0] = (f4v){0.f,0.f,0.f,0.f};
        p1[mt][1] = (f4v){0.f,0.f,0.f,0.f};
        p1[mt][0] = __builtin_amdgcn_mfma_f32_16x16x32_bf16(am, bu[0], p1[mt][0], 0,0,0);
        p1[mt][1] = __builtin_amdgcn_mfma_f32_16x16x32_bf16(am, bu[1], p1[mt][1], 0,0,0);
    }
    #pragma unroll
    for (int mt = 0; mt < 4; ++mt)
        #pragma unroll
        for (int ntl = 0; ntl < 2; ++ntl) {
            const int chunk = (2 * wv + ntl) * 16 + c;
            f4v v = p1[mt][ntl];
            unsigned int lo = cvt_pk_bf16(v[0], v[1]);
            unsigned int hi = cvt_pk_bf16(v[2], v[3]);
            *(uint2*)&ldsP[chunk * 36 + mt * 8 + 2 * g] = make_uint2(lo, hi);
        }
    __syncthreads();

    {
        const int n = tid & 31, seg = tid >> 5;
        const float wr_b = w32c[h * 64 + 2 * n];
        const float wi_b = w32c[h * 64 + 2 * n + 1];
        float sr = 0.f, si = 0.f;
        const int base = seg * 16;
        for (int t = 0; t < 16; ++t) {
            const int chunk = base + t;
            unsigned int pv = ldsP[chunk * 36 + n];
            ldsP[chunk * 36 + n] = cvt_pk_bf16(sr, si);
            float Pr = bf2f((unsigned short)(pv & 0xFFFF));
            float Pi = bf2f((unsigned short)(pv >> 16));
            float nsr = fmaf(wr_b, sr, fmaf(-wi_b, si, Pr));
            float nsi = fmaf(wr_b, si, fmaf(wi_b, sr, Pi));
            sr = nsr; si = nsi;
        }
        *(float2*)&ldsT[(seg * 32 + n) * 2] = make_float2(sr, si);
        __syncthreads();
        if (seg > 0) {
            float qr = wr_b, qi = wi_b;
            #pragma unroll
            for (int sq = 0; sq < 4; ++sq) {
                float nr = qr * qr - qi * qi;
                float ni = 2.0f * qr * qi;
                qr = nr; qi = ni;
            }
            float Qr = 0.f, Qi = 0.f;
            #pragma unroll
            for (int sp = 0; sp < 7; ++sp) {
                float2 Tv = *(const float2*)&ldsT[(sp * 32 + n) * 2];
                if (sp < seg) {
                    float nQr = fmaf(qr, Qr, fmaf(-qi, Qi, Tv.x));
                    float nQi = fmaf(qr, Qi, fmaf(qi, Qr, Tv.y));
                    Qr = nQr; Qi = nQi;
                }
            }
            float gr = Qr, gi = Qi;
            for (int t = 0; t < 16; ++t) {
                const int chunk = base + t;
                unsigned int sv = ldsP[chunk * 36 + n];
                float fr2 = bf2f((unsigned short)(sv & 0xFFFF)) + gr;
                float fi2 = bf2f((unsigned short)(sv >> 16)) + gi;
                ldsP[chunk * 36 + n] = cvt_pk_bf16(fr2, fi2);
                float ngr = wr_b * gr - wi_b * gi;
                float ngi = fmaf(wr_b, gi, wi_b * gr);
                gr = ngr; gi = ngi;
            }
        }
    }
    __syncthreads();

    const unsigned short* tmh = Tm + h * 1024;
    const unsigned short* emh = Em + h * 2048;
    const unsigned short* sbase = (const unsigned short*)ldsP;
    f4v a2[2][2];
    #pragma unroll
    for (int mt = 0; mt < 2; ++mt) {
        a2[mt][0] = (f4v){0.f,0.f,0.f,0.f};
        a2[mt][1] = (f4v){0.f,0.f,0.f,0.f};
        s8v at = *(const s8v*)(tmh + (mt * 16 + c) * 32 + g * 8);
        a2[mt][0] = __builtin_amdgcn_mfma_f32_16x16x32_bf16(at, bu[0], a2[mt][0], 0,0,0);
        a2[mt][1] = __builtin_amdgcn_mfma_f32_16x16x32_bf16(at, bu[1], a2[mt][1], 0,0,0);
    }
    #pragma unroll
    for (int ksub = 0; ksub < 2; ++ksub) {
        s8v bs[2];
        #pragma unroll
        for (int ntl = 0; ntl < 2; ++ntl) {
            const int chunk = (2 * wv + ntl) * 16 + c;
            bs[ntl] = *(const s8v*)(sbase + chunk * 72 + ksub * 32 + g * 8);
        }
        #pragma unroll
        for (int mt = 0; mt < 2; ++mt) {
            s8v ae = *(const s8v*)(emh + (mt * 16 + c) * 64 + ksub * 32 + g * 8);
            a2[mt][0] = __builtin_amdgcn_mfma_f32_16x16x32_bf16(ae, bs[0], a2[mt][0], 0,0,0);
            a2[mt][1] = __builtin_amdgcn_mfma_f32_16x16x32_bf16(ae, bs[1], a2[mt][1], 0,0,0);
        }
    }

    unsigned short* yrow = ybf + (size_t)bh * NL;
    #pragma unroll
    for (int mt = 0; mt < 2; ++mt)
        #pragma unroll
        for (int ntl = 0; ntl < 2; ++ntl) {
            const int chunk = (2 * wv + ntl) * 16 + c;
            f4v v = a2[mt][ntl];
            float gv[4];
            #pragma unroll
            for (int r = 0; r < 4; ++r) {
                float x = v[r];
                gv[r] = 0.5f * x * (1.0f + erff(x * 0.70710678118654752f));
            }
            unsigned int lo = cvt_pk_bf16(gv[0], gv[1]);
            unsigned int hi = cvt_pk_bf16(gv[2], gv[3]);
            *(uint2*)(yrow + chunk * 32 + mt * 16 + 4 * g) = make_uint2(lo, hi);
        }
}

// ---------------- MFMA GEMM + GLU: full-K LDS + LDS-transpose store epilogue ----------------
// K-loop unchanged (best measured). Epilogue: GLU in-reg -> ldsF[row][l] (stride 68,
// 2 chunks of 128 rows) -> each thread stores 4x contiguous float4 (64B runs,
// 256B per row-quad) instead of 32 scattered 4B stores.
__global__ __launch_bounds__(512) void gemm_glu_mfma(
        const unsigned short* __restrict__ ybf,
        const unsigned short* __restrict__ Wbf,
        const float* __restrict__ bo,
        float* __restrict__ out) {
    const int l0 = blockIdx.x * 64;
    const int b  = blockIdx.y;
    const int tid = threadIdx.x;
    const int lane = tid & 63;
    const int wv = tid >> 6;            // 0..7
    const int g = lane >> 4, c = lane & 15;

    __shared__ __align__(16) char arena[34816];  // max(64*132*4, 128*68*4)
    unsigned int* ldsY = (unsigned int*)arena;   // [64 l][132] u32 (K-loop)
    float*        ldsF = (float*)arena;          // [128 rows][68] f32 (epilogue)

    {
        const int r  = tid >> 1;
        const int hh = tid & 1;
        const int kp = r >> 1, hb = r & 1;
        const int kps = kp ^ (hh << 4);
        const unsigned short* ysrc = ybf + ((size_t)b * NH + r) * NL + l0 + hh * 32;
        uint4 v0 = ((const uint4*)ysrc)[0];
        uint4 v1 = ((const uint4*)ysrc)[1];
        uint4 v2 = ((const uint4*)ysrc)[2];
        uint4 v3 = ((const uint4*)ysrc)[3];
        unsigned short* lds16 = (unsigned short*)ldsY;
        const int base16 = ((hh * 32) * 132 + kps) * 2 + hb;
        u8h a0 = *(const u8h*)&v0, a1 = *(const u8h*)&v1;
        u8h a2 = *(const u8h*)&v2, a3 = *(const u8h*)&v3;
        #pragma unroll
        for (int j = 0; j < 8; ++j) {
            lds16[base16 + (j)      * 264] = a0[j];
            lds16[base16 + (j + 8)  * 264] = a1[j];
            lds16[base16 + (j + 16) * 264] = a2[j];
            lds16[base16 + (j + 24) * 264] = a3[j];
        }
    }
    __syncthreads();

    f4v acc[4][4];
    #pragma unroll
    for (int m = 0; m < 4; ++m)
        #pragma unroll
        for (int n = 0; n < 4; ++n)
            acc[m][n] = (f4v){0.f, 0.f, 0.f, 0.f};

    int wrow[4];
    wrow[0] = wv * 32 + c;
    wrow[1] = wrow[0] + 16;
    wrow[2] = wrow[0] + 256;
    wrow[3] = wrow[1] + 256;

    s8v afr[4];
    #pragma unroll
    for (int m = 0; m < 4; ++m)
        afr[m] = *(const s8v*)(Wbf + wrow[m] * NH + g * 8);

    #pragma unroll
    for (int ks = 0; ks < 8; ++ks) {
        s8v acur[4];
        #pragma unroll
        for (int m = 0; m < 4; ++m) acur[m] = afr[m];
        if (ks < 7) {
            #pragma unroll
            for (int m = 0; m < 4; ++m)
                afr[m] = *(const s8v*)(Wbf + wrow[m] * NH + (ks + 1) * 32 + g * 8);
        }
        s8v bfr[4];
        #pragma unroll
        for (int n = 0; n < 4; ++n) {
            const int colb = (ks * 16 + g * 4) ^ ((n >> 1) << 4);
            bfr[n] = *(const s8v*)&ldsY[(n * 16 + c) * 132 + colb];
        }
        #pragma unroll
        for (int m = 0; m < 4; ++m)
            #pragma unroll
            for (int n = 0; n < 4; ++n)
                acc[m][n] = __builtin_amdgcn_mfma_f32_16x16x32_bf16(
                    acur[m], bfr[n], acc[m][n], 0, 0, 0);
    }

    // ---- epilogue: GLU -> LDS transpose -> contiguous vector stores ----
    const int ro = tid >> 2, sg = tid & 3;
    #pragma unroll
    for (int m = 0; m < 2; ++m) {
        __syncthreads();  // ldsY reads (m=0) / previous chunk reads (m=1) complete
        const int o0 = wv * 32 + m * 16 + g * 4;
        float4 ba = *(const float4*)(bo + o0);
        float4 bb = *(const float4*)(bo + NH + o0);
        const float baj[4] = {ba.x, ba.y, ba.z, ba.w};
        const float bbj[4] = {bb.x, bb.y, bb.z, bb.w};
        #pragma unroll
        for (int j = 0; j < 4; ++j) {
            const int row = wv * 16 + g * 4 + j;   // 0..127 within chunk
            #pragma unroll
            for (int n = 0; n < 4; ++n) {
                float za = acc[m][n][j] + baj[j];
                float zb = acc[m + 2][n][j] + bbj[j];
                float s = __builtin_amdgcn_rcpf(1.0f + __expf(-zb));
                ldsF[row * 68 + n * 16 + c] = za * s;
            }
        }
        __syncthreads();
        // row ro of chunk -> global o = (ro>>4)*32 + m*16 + (ro&15)
        const int oo = ((ro >> 4) << 5) + m * 16 + (ro & 15);
        float* orow = out + ((size_t)(b * NH + oo)) * NL + l0 + sg * 16;
        const float* lsrc = &ldsF[ro * 68 + sg * 16];
        float4 q0 = *(const float4*)(lsrc);
        float4 q1 = *(const float4*)(lsrc + 4);
        float4 q2 = *(const float4*)(lsrc + 8);
        float4 q3 = *(const float4*)(lsrc + 12);
        *(float4*)(orow)      = q0;
        *(float4*)(orow + 4)  = q1;
        *(float4*)(orow + 8)  = q2;
        *(float4*)(orow + 12) = q3;
    }
}

extern "C" void kernel_launch(void* const* d_in, const int* in_sizes, int n_in,
                              void* d_out, int out_size, void* d_ws, size_t ws_size,
                              hipStream_t stream) {
    (void)in_sizes; (void)n_in; (void)out_size; (void)ws_size;
    const float* u      = (const float*)d_in[0];
    const float* log_dt = (const float*)d_in[1];
    const float* Cr     = (const float*)d_in[2];
    const float* Ci     = (const float*)d_in[3];
    const float* lar    = (const float*)d_in[4];
    const float* aim    = (const float*)d_in[5];
    const float* Dvec   = (const float*)d_in[6];
    const float* W      = (const float*)d_in[7];
    const float* bo     = (const float*)d_in[8];
    float* out = (float*)d_out;

    char* ws = (char*)d_ws;
    float*          w32c = (float*)ws;                          // 64 KB
    unsigned short* Mp   = (unsigned short*)(ws + 65536);       // 1 MB
    unsigned short* Em   = (unsigned short*)(ws + 1114112);     // 1 MB
    unsigned short* Tm   = (unsigned short*)(ws + 2162688);     // 512 KB
    unsigned short* Wbf  = (unsigned short*)(ws + 2686976);     // 256 KB
    unsigned short* ybf  = (unsigned short*)(ws + 2949120);     // 32 MB

    precompute_kernel<<<dim3(NH), dim3(64), 0, stream>>>(
        log_dt, Cr, Ci, lar, aim, Dvec, w32c, Mp, Em, Tm, W, Wbf);
    scan_mfma_kernel<<<dim3(NB * NH), dim3(256), 0, stream>>>(u, w32c, Mp, Tm, Em, ybf);
    gemm_glu_mfma<<<dim3(NL / 64, NB), dim3(512), 0, stream>>>(ybf, Wbf, bo, out);
}

// Round 21
// 77.840 us; speedup vs baseline: 1.3834x; 1.3834x over previous
//
#include <hip/hip_runtime.h>

#define NB 16
#define NH 256
#define NL 4096
#define NN 32

typedef short s8v __attribute__((ext_vector_type(8)));
typedef float f4v __attribute__((ext_vector_type(4)));
typedef unsigned short u8h __attribute__((ext_vector_type(8)));

__device__ __forceinline__ unsigned short f2bf(float x) {
    unsigned int u = __float_as_uint(x);
    unsigned int r = u + 0x7FFFu + ((u >> 16) & 1u);
    return (unsigned short)(r >> 16);
}
__device__ __forceinline__ float bf2f(unsigned short b) {
    return __uint_as_float(((unsigned int)b) << 16);
}
// HW pack: two f32 -> one u32 holding (lo=src0, hi=src1) as bf16 (RNE).
__device__ __forceinline__ unsigned int cvt_pk_bf16(float lo, float hi) {
    unsigned int r;
    asm("v_cvt_pk_bf16_f32 %0, %1, %2" : "=v"(r) : "v"(lo), "v"(hi));
    return r;
}

// ---------- merged precompute + W fragment-packing ----------
// Wpk fragment layout (16B units): idx = ((m*8+wv)*8+ks)*64 + lane, lane=(g<<4)|c
//   holds W[wv*32 + c + moff[m]][ks*32 + g*8 .. +7] as bf16x8, moff={0,16,256,272}.
// Gemm A-loads become base + lane*16 -> one contiguous 1KB request per wave instr.
__global__ __launch_bounds__(64) void precompute_kernel(
        const float* __restrict__ log_dt,
        const float* __restrict__ Cr,
        const float* __restrict__ Ci,
        const float* __restrict__ lar,
        const float* __restrict__ aim,
        const float* __restrict__ Dvec,
        float* __restrict__ w32c,
        unsigned short* __restrict__ Mp,
        unsigned short* __restrict__ Em,
        unsigned short* __restrict__ Tm,
        const float* __restrict__ W,
        unsigned short* __restrict__ Wpk) {
    const int h = blockIdx.x;
    const int tid = threadIdx.x;
    __shared__ float sRe[32][33];
    __shared__ float sTd[32];
    __shared__ unsigned short sMp[64 * 32];
    __shared__ unsigned short sEm[32 * 64];

    if (tid < 32) {
        const int n = tid;
        const int idx = h * 32 + n;
        float dt = expf(log_dt[h]);
        float ar = -expf(lar[idx]);
        float ai = aim[idx];
        float dar = ar * dt, dai = ai * dt;
        float er = expf(dar);
        float wr = er * cosf(dai), wi = er * sinf(dai);
        float Er = wr - 1.0f, Ei = wi;
        float den = ar * ar + ai * ai;
        float fr = (Er * ar + Ei * ai) / den;
        float fi = (Ei * ar - Er * ai) / den;
        float cr = Cr[idx], ci = Ci[idx];
        float c2r = 2.0f * (cr * fr - ci * fi);
        float c2i = 2.0f * (cr * fi + ci * fr);
        float e32 = expf(32.0f * dar);
        w32c[h * 64 + 2 * n]     = e32 * cosf(32.0f * dai);
        w32c[h * 64 + 2 * n + 1] = e32 * sinf(32.0f * dai);
        float pr = 1.0f, pi = 0.0f;
        for (int e = 0; e < 32; ++e) {
            sMp[(2 * n) * 32 + (31 - e)]     = f2bf(pr);
            sMp[(2 * n + 1) * 32 + (31 - e)] = f2bf(pi);
            float npr = pr * wr - pi * wi;
            pi = fmaf(pr, wi, pi * wr);
            pr = npr;
        }
        float gr = c2r, gi = c2i;
        for (int e = 0; e <= 32; ++e) {
            if (e < 32) sRe[e][n] = gr;
            if (e >= 1) {
                sEm[(e - 1) * 64 + 2 * n]     = f2bf(gr);
                sEm[(e - 1) * 64 + 2 * n + 1] = f2bf(-gi);
            }
            float ngr = gr * wr - gi * wi;
            gi = fmaf(gr, wi, gi * wr);
            gr = ngr;
        }
    }
    __syncthreads();
    if (tid < 32) {
        float a = 0.0f;
        #pragma unroll
        for (int n = 0; n < 32; ++n) a += sRe[tid][n];
        sTd[tid] = a;
    }
    __syncthreads();
    const float dh = Dvec[h];
    unsigned short* tmh = Tm + h * 1024;
    for (int i = 0; i < 16; ++i) {
        int idx = tid * 16 + i;
        int j = idx >> 5, tt = idx & 31;
        float v = (j >= tt) ? sTd[j - tt] : 0.0f;
        if (j == tt) v += dh;
        tmh[idx] = f2bf(v);
    }
    uint4* mp4 = (uint4*)(Mp + h * 2048);
    uint4* em4 = (uint4*)(Em + h * 2048);
    const uint4* smp4 = (const uint4*)sMp;
    const uint4* sem4 = (const uint4*)sEm;
    #pragma unroll
    for (int k = 0; k < 4; ++k) {
        mp4[k * 64 + tid] = smp4[k * 64 + tid];
        em4[k * 64 + tid] = sem4[k * 64 + tid];
    }
    // ---- W fragment packing: one 16B fragment per thread ----
    {
        const int fragid = h * 64 + tid;           // 0..16383
        const int lane = fragid & 63;
        const int rest = fragid >> 6;              // (m*8+wv)*8+ks
        const int ks  = rest & 7;
        const int wvq = (rest >> 3) & 7;
        const int m   = rest >> 6;
        const int g = lane >> 4, c = lane & 15;
        const int moff4[4] = {0, 16, 256, 272};
        const int row = wvq * 32 + c + moff4[m];
        const float* wsrc = W + row * NH + ks * 32 + g * 8;
        float4 wa = *(const float4*)wsrc;
        float4 wb = *(const float4*)(wsrc + 4);
        union { unsigned int w[4]; uint4 q; } pk;
        pk.w[0] = cvt_pk_bf16(wa.x, wa.y);
        pk.w[1] = cvt_pk_bf16(wa.z, wa.w);
        pk.w[2] = cvt_pk_bf16(wb.x, wb.y);
        pk.w[3] = cvt_pk_bf16(wb.z, wb.w);
        ((uint4*)Wpk)[fragid] = pk.q;
    }
}

// ---------- MFMA chunked scan: 8-segment phase B on all 4 waves (unchanged) ----------
__global__ __launch_bounds__(256) void scan_mfma_kernel(
        const float* __restrict__ u,
        const float* __restrict__ w32c,
        const unsigned short* __restrict__ Mp,
        const unsigned short* __restrict__ Tm,
        const unsigned short* __restrict__ Em,
        unsigned short* __restrict__ ybf) {
    const int bh = blockIdx.x;
    const int h = bh & (NH - 1);
    const int tid = threadIdx.x;
    const int lane = tid & 63;
    const int wv = tid >> 6;
    const int g = lane >> 4, c = lane & 15;

    __shared__ float ldsT[512];
    __shared__ __align__(16) unsigned int ldsP[128 * 36];

    s8v bu[2];
    #pragma unroll
    for (int ntl = 0; ntl < 2; ++ntl) {
        const float* usrc = u + (size_t)bh * NL + (((2 * wv + ntl) * 16 + c) << 5) + g * 8;
        float4 x0 = *(const float4*)usrc;
        float4 x1 = *(const float4*)(usrc + 4);
        union { unsigned int w[4]; s8v v; } cv;
        cv.w[0] = cvt_pk_bf16(x0.x, x0.y);
        cv.w[1] = cvt_pk_bf16(x0.z, x0.w);
        cv.w[2] = cvt_pk_bf16(x1.x, x1.y);
        cv.w[3] = cvt_pk_bf16(x1.z, x1.w);
        bu[ntl] = cv.v;
    }

    const unsigned short* mph = Mp + h * 2048;
    f4v p1[4][2];
    #pragma unroll
    for (int mt = 0; mt < 4; ++mt) {
        s8v am = *(const s8v*)(mph + (mt * 16 + c) * 32 + g * 8);
        p1[mt][0] = (f4v){0.f,0.f,0.f,0.f};
        p1[mt][1] = (f4v){0.f,0.f,0.f,0.f};
        p1[mt][0] = __builtin_amdgcn_mfma_f32_16x16x32_bf16(am, bu[0], p1[mt][0], 0,0,0);
        p1[mt][1] = __builtin_amdgcn_mfma_f32_16x16x32_bf16(am, bu[1], p1[mt][1], 0,0,0);
    }
    #pragma unroll
    for (int mt = 0; mt < 4; ++mt)
        #pragma unroll
        for (int ntl = 0; ntl < 2; ++ntl) {
            const int chunk = (2 * wv + ntl) * 16 + c;
            f4v v = p1[mt][ntl];
            unsigned int lo = cvt_pk_bf16(v[0], v[1]);
            unsigned int hi = cvt_pk_bf16(v[2], v[3]);
            *(uint2*)&ldsP[chunk * 36 + mt * 8 + 2 * g] = make_uint2(lo, hi);
        }
    __syncthreads();

    {
        const int n = tid & 31, seg = tid >> 5;
        const float wr_b = w32c[h * 64 + 2 * n];
        const float wi_b = w32c[h * 64 + 2 * n + 1];
        float sr = 0.f, si = 0.f;
        const int base = seg * 16;
        for (int t = 0; t < 16; ++t) {
            const int chunk = base + t;
            unsigned int pv = ldsP[chunk * 36 + n];
            ldsP[chunk * 36 + n] = cvt_pk_bf16(sr, si);
            float Pr = bf2f((unsigned short)(pv & 0xFFFF));
            float Pi = bf2f((unsigned short)(pv >> 16));
            float nsr = fmaf(wr_b, sr, fmaf(-wi_b, si, Pr));
            float nsi = fmaf(wr_b, si, fmaf(wi_b, sr, Pi));
            sr = nsr; si = nsi;
        }
        *(float2*)&ldsT[(seg * 32 + n) * 2] = make_float2(sr, si);
        __syncthreads();
        if (seg > 0) {
            float qr = wr_b, qi = wi_b;
            #pragma unroll
            for (int sq = 0; sq < 4; ++sq) {
                float nr = qr * qr - qi * qi;
                float ni = 2.0f * qr * qi;
                qr = nr; qi = ni;
            }
            float Qr = 0.f, Qi = 0.f;
            #pragma unroll
            for (int sp = 0; sp < 7; ++sp) {
                float2 Tv = *(const float2*)&ldsT[(sp * 32 + n) * 2];
                if (sp < seg) {
                    float nQr = fmaf(qr, Qr, fmaf(-qi, Qi, Tv.x));
                    float nQi = fmaf(qr, Qi, fmaf(qi, Qr, Tv.y));
                    Qr = nQr; Qi = nQi;
                }
            }
            float gr = Qr, gi = Qi;
            for (int t = 0; t < 16; ++t) {
                const int chunk = base + t;
                unsigned int sv = ldsP[chunk * 36 + n];
                float fr2 = bf2f((unsigned short)(sv & 0xFFFF)) + gr;
                float fi2 = bf2f((unsigned short)(sv >> 16)) + gi;
                ldsP[chunk * 36 + n] = cvt_pk_bf16(fr2, fi2);
                float ngr = wr_b * gr - wi_b * gi;
                float ngi = fmaf(wr_b, gi, wi_b * gr);
                gr = ngr; gi = ngi;
            }
        }
    }
    __syncthreads();

    const unsigned short* tmh = Tm + h * 1024;
    const unsigned short* emh = Em + h * 2048;
    const unsigned short* sbase = (const unsigned short*)ldsP;
    f4v a2[2][2];
    #pragma unroll
    for (int mt = 0; mt < 2; ++mt) {
        a2[mt][0] = (f4v){0.f,0.f,0.f,0.f};
        a2[mt][1] = (f4v){0.f,0.f,0.f,0.f};
        s8v at = *(const s8v*)(tmh + (mt * 16 + c) * 32 + g * 8);
        a2[mt][0] = __builtin_amdgcn_mfma_f32_16x16x32_bf16(at, bu[0], a2[mt][0], 0,0,0);
        a2[mt][1] = __builtin_amdgcn_mfma_f32_16x16x32_bf16(at, bu[1], a2[mt][1], 0,0,0);
    }
    #pragma unroll
    for (int ksub = 0; ksub < 2; ++ksub) {
        s8v bs[2];
        #pragma unroll
        for (int ntl = 0; ntl < 2; ++ntl) {
            const int chunk = (2 * wv + ntl) * 16 + c;
            bs[ntl] = *(const s8v*)(sbase + chunk * 72 + ksub * 32 + g * 8);
        }
        #pragma unroll
        for (int mt = 0; mt < 2; ++mt) {
            s8v ae = *(const s8v*)(emh + (mt * 16 + c) * 64 + ksub * 32 + g * 8);
            a2[mt][0] = __builtin_amdgcn_mfma_f32_16x16x32_bf16(ae, bs[0], a2[mt][0], 0,0,0);
            a2[mt][1] = __builtin_amdgcn_mfma_f32_16x16x32_bf16(ae, bs[1], a2[mt][1], 0,0,0);
        }
    }

    unsigned short* yrow = ybf + (size_t)bh * NL;
    #pragma unroll
    for (int mt = 0; mt < 2; ++mt)
        #pragma unroll
        for (int ntl = 0; ntl < 2; ++ntl) {
            const int chunk = (2 * wv + ntl) * 16 + c;
            f4v v = a2[mt][ntl];
            float gv[4];
            #pragma unroll
            for (int r = 0; r < 4; ++r) {
                float x = v[r];
                gv[r] = 0.5f * x * (1.0f + erff(x * 0.70710678118654752f));
            }
            unsigned int lo = cvt_pk_bf16(gv[0], gv[1]);
            unsigned int hi = cvt_pk_bf16(gv[2], gv[3]);
            *(uint2*)(yrow + chunk * 32 + mt * 16 + 4 * g) = make_uint2(lo, hi);
        }
}

// ---------------- MFMA GEMM + GLU: full-K LDS + coalesced Wpk fragment loads ----------------
// R17 structure (best measured 48.2us); A-loads now base + lane*16 (1KB/wave/instr).
__global__ __launch_bounds__(512) void gemm_glu_mfma(
        const unsigned short* __restrict__ ybf,
        const unsigned short* __restrict__ Wpk,
        const float* __restrict__ bo,
        float* __restrict__ out) {
    const int l0 = blockIdx.x * 64;
    const int b  = blockIdx.y;
    const int tid = threadIdx.x;
    const int lane = tid & 63;
    const int wv = tid >> 6;            // 0..7
    const int g = lane >> 4, c = lane & 15;

    __shared__ __align__(16) unsigned int ldsY[64 * 132];  // 33792 B

    {
        const int r  = tid >> 1;
        const int hh = tid & 1;
        const int kp = r >> 1, hb = r & 1;
        const int kps = kp ^ (hh << 4);
        const unsigned short* ysrc = ybf + ((size_t)b * NH + r) * NL + l0 + hh * 32;
        uint4 v0 = ((const uint4*)ysrc)[0];
        uint4 v1 = ((const uint4*)ysrc)[1];
        uint4 v2 = ((const uint4*)ysrc)[2];
        uint4 v3 = ((const uint4*)ysrc)[3];
        unsigned short* lds16 = (unsigned short*)ldsY;
        const int base16 = ((hh * 32) * 132 + kps) * 2 + hb;
        u8h a0 = *(const u8h*)&v0, a1 = *(const u8h*)&v1;
        u8h a2 = *(const u8h*)&v2, a3 = *(const u8h*)&v3;
        #pragma unroll
        for (int j = 0; j < 8; ++j) {
            lds16[base16 + (j)      * 264] = a0[j];
            lds16[base16 + (j + 8)  * 264] = a1[j];
            lds16[base16 + (j + 16) * 264] = a2[j];
            lds16[base16 + (j + 24) * 264] = a3[j];
        }
    }
    __syncthreads();

    f4v acc[4][4];
    #pragma unroll
    for (int m = 0; m < 4; ++m)
        #pragma unroll
        for (int n = 0; n < 4; ++n)
            acc[m][n] = (f4v){0.f, 0.f, 0.f, 0.f};

    // coalesced fragment bases: frag idx = ((m*8+wv)*8+ks)*64 + lane, 8 bf16 each
    const unsigned short* wfrag[4];
    #pragma unroll
    for (int m = 0; m < 4; ++m)
        wfrag[m] = Wpk + ((((m * 8 + wv) * 8) * 64) + lane) * 8;

    s8v afr[4];
    #pragma unroll
    for (int m = 0; m < 4; ++m)
        afr[m] = *(const s8v*)(wfrag[m]);

    #pragma unroll
    for (int ks = 0; ks < 8; ++ks) {
        s8v acur[4];
        #pragma unroll
        for (int m = 0; m < 4; ++m) acur[m] = afr[m];
        if (ks < 7) {
            #pragma unroll
            for (int m = 0; m < 4; ++m)
                afr[m] = *(const s8v*)(wfrag[m] + (ks + 1) * 64 * 8);
        }
        s8v bfr[4];
        #pragma unroll
        for (int n = 0; n < 4; ++n) {
            const int colb = (ks * 16 + g * 4) ^ ((n >> 1) << 4);
            bfr[n] = *(const s8v*)&ldsY[(n * 16 + c) * 132 + colb];
        }
        #pragma unroll
        for (int m = 0; m < 4; ++m)
            #pragma unroll
            for (int n = 0; n < 4; ++n)
                acc[m][n] = __builtin_amdgcn_mfma_f32_16x16x32_bf16(
                    acur[m], bfr[n], acc[m][n], 0, 0, 0);
    }

    #pragma unroll
    for (int m = 0; m < 2; ++m) {
        const int o0 = wv * 32 + m * 16 + g * 4;
        float4 ba = *(const float4*)(bo + o0);
        float4 bb = *(const float4*)(bo + NH + o0);
        const float baj[4] = {ba.x, ba.y, ba.z, ba.w};
        const float bbj[4] = {bb.x, bb.y, bb.z, bb.w};
        #pragma unroll
        for (int j = 0; j < 4; ++j) {
            float* orow = out + ((size_t)(b * NH + o0 + j)) * NL + l0 + c;
            #pragma unroll
            for (int n = 0; n < 4; ++n) {
                float za = acc[m][n][j] + baj[j];
                float zb = acc[m + 2][n][j] + bbj[j];
                float s = __builtin_amdgcn_rcpf(1.0f + __expf(-zb));
                orow[n * 16] = za * s;
            }
        }
    }
}

extern "C" void kernel_launch(void* const* d_in, const int* in_sizes, int n_in,
                              void* d_out, int out_size, void* d_ws, size_t ws_size,
                              hipStream_t stream) {
    (void)in_sizes; (void)n_in; (void)out_size; (void)ws_size;
    const float* u      = (const float*)d_in[0];
    const float* log_dt = (const float*)d_in[1];
    const float* Cr     = (const float*)d_in[2];
    const float* Ci     = (const float*)d_in[3];
    const float* lar    = (const float*)d_in[4];
    const float* aim    = (const float*)d_in[5];
    const float* Dvec   = (const float*)d_in[6];
    const float* W      = (const float*)d_in[7];
    const float* bo     = (const float*)d_in[8];
    float* out = (float*)d_out;

    char* ws = (char*)d_ws;
    float*          w32c = (float*)ws;                          // 64 KB
    unsigned short* Mp   = (unsigned short*)(ws + 65536);       // 1 MB
    unsigned short* Em   = (unsigned short*)(ws + 1114112);     // 1 MB
    unsigned short* Tm   = (unsigned short*)(ws + 2162688);     // 512 KB
    unsigned short* Wpk  = (unsigned short*)(ws + 2686976);     // 256 KB
    unsigned short* ybf  = (unsigned short*)(ws + 2949120);     // 32 MB

    precompute_kernel<<<dim3(NH), dim3(64), 0, stream>>>(
        log_dt, Cr, Ci, lar, aim, Dvec, w32c, Mp, Em, Tm, W, Wpk);
    scan_mfma_kernel<<<dim3(NB * NH), dim3(256), 0, stream>>>(u, w32c, Mp, Tm, Em, ybf);
    gemm_glu_mfma<<<dim3(NL / 64, NB), dim3(512), 0, stream>>>(ybf, Wpk, bo, out);
}